// Round 4
// baseline (467.254 us; speedup 1.0000x reference)
//
#include <hip/hip_runtime.h>

// MQCCLayer forward on MI355X.
// conv(x/mag, w) * mag == conv(x, w) (conv linear in x) -> sample L2 norm cancels.
// OUT_CHANNELS == C*F -> slice is a no-op. Remaining: depthwise 3x3 same-pad conv,
// F=2 shared unit-norm filters (cross-correlation, no flip).
//
// R4 = MEASUREMENT PROBE: identical work repeated REPEAT times in ONE dispatch
// (grid x3, every rep writes the full identical output). Purpose: push the
// kernel dispatch above the 165us fill dispatches so it appears in the rocprof
// top-5 (first-ever counters for this kernel), and k = (dur - 363)/2.
// Next round reverts to REPEAT=1.

#define BATCH 32
#define CIN   4
#define HH    512
#define WW    512
#define NF    2
#define W4    (WW / 4)    // 128 col-quads per row
#define HG    (HH / 4)    // 128 row-groups per image
#define NXCD  8
#define REPEAT 3
#define TASKS  (BATCH * CIN * HG * W4 / 256)   // 8192 blocks of real work

typedef float floatx4 __attribute__((ext_vector_type(4)));

__global__ __launch_bounds__(256) void mqcc_kernel(
    const float* __restrict__ x,
    const float* __restrict__ angles,
    float* __restrict__ out)
{
    // --- normalized filters (uniform -> scalar loads/ops) ---
    float wf[NF][9];
#pragma unroll
    for (int f = 0; f < NF; ++f) {
        float s = 0.f;
#pragma unroll
        for (int k = 0; k < 9; ++k) { float a = angles[f * 9 + k]; s += a * a; }
        float inv = rsqrtf(s);
#pragma unroll
        for (int k = 0; k < 9; ++k) wf[f][k] = angles[f * 9 + k] * inv;
    }

    // bijective XCD swizzle over the FULL grid (24576 % 8 == 0), then fold
    // into task space: all REPEAT reps perform identical full work.
    int bid  = blockIdx.x;
    int wid  = (bid & (NXCD - 1)) * (gridDim.x / NXCD) + (bid / NXCD);
    int task = wid & (TASKS - 1);          // wid mod 8192 (power of 2)
    int tid  = task * 256 + threadIdx.x;

    // bits: w4 [0..6], hgroup [7..13], c [14..15], b [16..20]
    int w4 = tid & (W4 - 1);
    int hg = (tid >> 7) & (HG - 1);
    int c  = (tid >> 14) & (CIN - 1);
    int b  = tid >> 16;

    int w0    = w4 << 2;
    int hbase = hg << 2;
    int lane  = threadIdx.x & 63;
    const float* xp = x + ((size_t)(b * CIN + c) * HH) * WW;

    float acc[4][NF][4];
#pragma unroll
    for (int j = 0; j < 4; ++j)
#pragma unroll
        for (int f = 0; f < NF; ++f)
#pragma unroll
            for (int q = 0; q < 4; ++q) acc[j][f][q] = 0.f;

    // rolling window over 6 input rows: ri = hbase-1 .. hbase+4
#pragma unroll
    for (int i = 0; i < 6; ++i) {
        int ri = hbase + i - 1;
        if (ri >= 0 && ri < HH) {          // wave-uniform (hg uniform per wave)
            const float* row = xp + (size_t)ri * WW;
            floatx4 v = *(const floatx4*)(row + w0);
            float l  = __shfl_up(v.w, 1, 64);
            float rt = __shfl_down(v.x, 1, 64);
            if (lane == 0)  l  = (w4 == 0)      ? 0.f : row[w0 - 1];
            if (lane == 63) rt = (w4 == W4 - 1) ? 0.f : row[w0 + 4];
            float e[6] = { l, v.x, v.y, v.z, v.w, rt };
#pragma unroll
            for (int kh = 0; kh < 3; ++kh) {
                int j = i - kh;
                if (j >= 0 && j < 4) {
#pragma unroll
                    for (int f = 0; f < NF; ++f) {
                        float wv0 = wf[f][kh * 3 + 0];
                        float wv1 = wf[f][kh * 3 + 1];
                        float wv2 = wf[f][kh * 3 + 2];
#pragma unroll
                        for (int q = 0; q < 4; ++q) {
                            float s = acc[j][f][q];
                            s = fmaf(wv0, e[q + 0], s);
                            s = fmaf(wv1, e[q + 1], s);
                            s = fmaf(wv2, e[q + 2], s);
                            acc[j][f][q] = s;
                        }
                    }
                }
            }
        }
    }

    // epilogue: 8 nontemporal 16B stores (identical values across reps -> benign)
#pragma unroll
    for (int j = 0; j < 4; ++j) {
#pragma unroll
        for (int f = 0; f < NF; ++f) {
            floatx4 o = { acc[j][f][0], acc[j][f][1], acc[j][f][2], acc[j][f][3] };
            float* op = out + ((((size_t)b * (CIN * NF) + (c * NF + f)) * HH + (hbase + j)) * WW + w0);
            __builtin_nontemporal_store(o, (floatx4*)op);
        }
    }
}

extern "C" void kernel_launch(void* const* d_in, const int* in_sizes, int n_in,
                              void* d_out, int out_size, void* d_ws, size_t ws_size,
                              hipStream_t stream) {
    const float* x      = (const float*)d_in[0];
    const float* angles = (const float*)d_in[1];
    float* out          = (float*)d_out;

    const int block = 256;
    const int grid  = REPEAT * TASKS;   // 24576, divisible by 8 (swizzle bijective)

    hipLaunchKernelGGL(mqcc_kernel, dim3(grid), dim3(block), 0, stream,
                       x, angles, out);
}

// Round 5
// 367.243 us; speedup vs baseline: 1.2723x; 1.2723x over previous
//
#include <hip/hip_runtime.h>

// MQCCLayer forward on MI355X.
// conv(x/mag, w) * mag == conv(x, w) (conv linear in x) -> sample L2 norm cancels.
// OUT_CHANNELS == C*F -> slice is a no-op. Remaining: depthwise 3x3 same-pad conv,
// F=2 shared unit-norm filters (cross-correlation, no flip).
//
// R5 structure: ONE WAVE = ONE FULL 512-col ROW SPAN, 4 output rows per thread.
// Lane i owns cols [4i..4i+3] (segment A) and [256+4i..256+4i+3] (segment B):
// per row exactly two contiguous 1KB wave loads (lane i -> quad i, quad 64+i).
// All horizontal edges come from in-wave shfl + cndmask -> ZERO per-lane edge
// loads, ZERO divergent branches (R4 counters showed issue-rate/latency bound:
// 59% HBM, 25% VALU, 40% occ; 12 of 18 load insts were 1-lane edge loads).
// All 12 row loads issued upfront for MLP. nt stores (out never re-read).

#define BATCH 32
#define CIN   4
#define HH    512
#define WW    512
#define NF    2
#define RPT   4            // output rows per thread
#define HG    (HH / RPT)   // 128 row groups
#define NXCD  8

typedef float floatx4 __attribute__((ext_vector_type(4)));

__global__ __launch_bounds__(256) void mqcc_kernel(
    const float* __restrict__ x,
    const float* __restrict__ angles,
    float* __restrict__ out)
{
    // --- normalized filters (uniform -> scalar) ---
    float wf[NF][9];
#pragma unroll
    for (int f = 0; f < NF; ++f) {
        float s = 0.f;
#pragma unroll
        for (int k = 0; k < 9; ++k) { float a = angles[f * 9 + k]; s += a * a; }
        float inv = rsqrtf(s);
#pragma unroll
        for (int k = 0; k < 9; ++k) wf[f][k] = angles[f * 9 + k] * inv;
    }

    // bijective XCD swizzle: grid 4096, chunk 512 per XCD.
    int bid   = blockIdx.x;
    int wid   = ((bid & (NXCD - 1)) << 9) + (bid >> 3);
    int gwave = wid * 4 + (threadIdx.x >> 6);   // 16384 waves
    int lane  = threadIdx.x & 63;

    // gwave bits: hg [0..6], c [7..8], b [9..13]  (block = 4 consecutive hg)
    int hg = gwave & (HG - 1);
    int c  = (gwave >> 7) & (CIN - 1);
    int b  = gwave >> 9;

    int hbase = hg * RPT;
    int col   = lane << 2;                       // segment A base; B = col+256
    const float* xp = x + ((size_t)(b * CIN + c) * HH) * WW;

    // --- all 12 loads upfront (6 rows x 2 segments), zero-fill at v-borders ---
    floatx4 va[6], vb[6];
#pragma unroll
    for (int i = 0; i < 6; ++i) {
        int ri = hbase + i - 1;
        if (ri >= 0 && ri < HH) {                // wave-uniform
            const float* row = xp + (size_t)ri * WW;
            va[i] = *(const floatx4*)(row + col);
            vb[i] = *(const floatx4*)(row + col + 256);
        } else {
            va[i] = 0.f; vb[i] = 0.f;
        }
    }

    float accA[RPT][NF][4], accB[RPT][NF][4];
#pragma unroll
    for (int j = 0; j < RPT; ++j)
#pragma unroll
        for (int f = 0; f < NF; ++f)
#pragma unroll
            for (int q = 0; q < 4; ++q) { accA[j][f][q] = 0.f; accB[j][f][q] = 0.f; }

#pragma unroll
    for (int i = 0; i < 6; ++i) {
        floatx4 a = va[i], bq = vb[i];
        // horizontal neighbors, all in-wave (cndmask, no branches):
        float a_l = __shfl_up(a.w, 1, 64);       // lane0 junk -> col -1 = 0
        float a_r = __shfl_down(a.x, 1, 64);     // lane63 junk -> col 256
        float b_l = __shfl_up(bq.w, 1, 64);      // lane0 junk -> col 255
        float b_r = __shfl_down(bq.x, 1, 64);    // lane63 junk -> col 512 = 0
        float a255 = __shfl(a.w, 63, 64);
        float b256 = __shfl(bq.x, 0, 64);
        a_l = (lane == 0)  ? 0.f  : a_l;
        b_l = (lane == 0)  ? a255 : b_l;
        a_r = (lane == 63) ? b256 : a_r;
        b_r = (lane == 63) ? 0.f  : b_r;

        float eA[6] = { a_l, a.x, a.y, a.z, a.w, a_r };
        float eB[6] = { b_l, bq.x, bq.y, bq.z, bq.w, b_r };

        // input row i feeds output row j = i - kh
#pragma unroll
        for (int kh = 0; kh < 3; ++kh) {
            int j = i - kh;
            if (j >= 0 && j < RPT) {
#pragma unroll
                for (int f = 0; f < NF; ++f) {
                    float w0 = wf[f][kh * 3 + 0];
                    float w1 = wf[f][kh * 3 + 1];
                    float w2 = wf[f][kh * 3 + 2];
#pragma unroll
                    for (int q = 0; q < 4; ++q) {
                        float sA = accA[j][f][q];
                        sA = fmaf(w0, eA[q + 0], sA);
                        sA = fmaf(w1, eA[q + 1], sA);
                        sA = fmaf(w2, eA[q + 2], sA);
                        accA[j][f][q] = sA;
                        float sB = accB[j][f][q];
                        sB = fmaf(w0, eB[q + 0], sB);
                        sB = fmaf(w1, eB[q + 1], sB);
                        sB = fmaf(w2, eB[q + 2], sB);
                        accB[j][f][q] = sB;
                    }
                }
            }
        }
    }

    // --- epilogue: 16 nt 16B stores, contiguous per wave ---
#pragma unroll
    for (int j = 0; j < RPT; ++j) {
#pragma unroll
        for (int f = 0; f < NF; ++f) {
            float* op = out + ((((size_t)b * (CIN * NF) + (c * NF + f)) * HH + (hbase + j)) * WW);
            floatx4 oA = { accA[j][f][0], accA[j][f][1], accA[j][f][2], accA[j][f][3] };
            floatx4 oB = { accB[j][f][0], accB[j][f][1], accB[j][f][2], accB[j][f][3] };
            __builtin_nontemporal_store(oA, (floatx4*)(op + col));
            __builtin_nontemporal_store(oB, (floatx4*)(op + col + 256));
        }
    }
}

extern "C" void kernel_launch(void* const* d_in, const int* in_sizes, int n_in,
                              void* d_out, int out_size, void* d_ws, size_t ws_size,
                              hipStream_t stream) {
    const float* x      = (const float*)d_in[0];
    const float* angles = (const float*)d_in[1];
    float* out          = (float*)d_out;

    // waves = B*C*HG = 32*4*128 = 16384 -> 4096 blocks of 256 (div by 8)
    const int grid  = BATCH * CIN * HG / 4;
    const int block = 256;

    hipLaunchKernelGGL(mqcc_kernel, dim3(grid), dim3(block), 0, stream,
                       x, angles, out);
}